// Round 5
// baseline (3031.756 us; speedup 1.0000x reference)
//
#include <hip/hip_runtime.h>
#include <hip/hip_bf16.h>

namespace {

constexpr int B  = 32;
constexpr int L  = 100;
constexpr int S  = 501;
constexpr int DK = 64;
constexpr int DE = 128;

__device__ __forceinline__ float sigm(float x) {
    return __fdividef(1.0f, 1.0f + __expf(-x));
}

// ---------------- init: transpose weights (k-major), zero counters, pred[:,0]
__global__ __launch_bounds__(256) void k_init(
    const float* __restrict__ W1, const float* __restrict__ W2,
    const float* __restrict__ W3, const float* __restrict__ W4,
    const float* __restrict__ W5,
    float* __restrict__ W1T, float* __restrict__ W2T, float* __restrict__ W3T,
    float* __restrict__ W4T, float* __restrict__ W5T,
    unsigned* __restrict__ cnt, float* __restrict__ pred)
{
    const int idx = blockIdx.x * 256 + threadIdx.x;
    const int st  = gridDim.x * 256;
    for (int i = idx; i < 64 * 256; i += st) {
        int dd = i >> 8, kk = i & 255;
        W1T[kk * 64 + dd] = W1[i];
        W2T[kk * 64 + dd] = W2[i];
        W3T[kk * 64 + dd] = W3[i];
    }
    for (int i = idx; i < 64 * 192; i += st) {
        int dd = i / 192, kk = i % 192;
        W4T[kk * 64 + dd] = W4[i];
        W5T[kk * 64 + dd] = W5[i];
    }
    if (idx < B) { cnt[idx] = 0u; pred[idx * L] = 0.0f; }
}

// ---------------- all_learning = concat(e,at,a) @ W1^T + b1 ----------------
__global__ __launch_bounds__(256) void k_all_learning(
    const int* __restrict__ e_data, const int* __restrict__ a_data,
    const int* __restrict__ at_data,
    const float* __restrict__ e_embed, const float* __restrict__ at_embed,
    const float* __restrict__ W1T, const float* __restrict__ b1,
    float* __restrict__ allL)
{
    __shared__ float in_s[4][257];
    const int g = threadIdx.x >> 6;
    const int d = threadIdx.x & 63;
    const int row = blockIdx.x * 4 + g;
    const int e  = e_data[row];
    const int at = at_data[row];
    in_s[g][d]       = e_embed[(size_t)e * DE + d];
    in_s[g][64 + d]  = e_embed[(size_t)e * DE + 64 + d];
    in_s[g][128 + d] = at_embed[(size_t)at * DK + d];
    in_s[g][192 + d] = (float)a_data[row];
    __syncthreads();
    float acc = b1[d];
    #pragma unroll 8
    for (int k = 0; k < 256; ++k) acc += W1T[k * 64 + d] * in_s[g][k];
    allL[row * DK + d] = acc;
}

// ---------------- G2,G3 (non-recurrent parts), G4it, prey ------------------
__global__ __launch_bounds__(256) void k_pre(
    const int* __restrict__ e_data, const int* __restrict__ it_data,
    const float* __restrict__ e_embed, const float* __restrict__ it_embed,
    const float* __restrict__ allL,
    const float* __restrict__ W2T, const float* __restrict__ W3T,
    const float* __restrict__ W4T, const float* __restrict__ W5T,
    const float* __restrict__ b2, const float* __restrict__ b3,
    const float* __restrict__ b4, const float* __restrict__ b5,
    float* __restrict__ G2, float* __restrict__ G3,
    float* __restrict__ G4it, float* __restrict__ prey)
{
    __shared__ float lp[4][64], its[4][64], ln[4][64], ee[4][128];
    const int g = threadIdx.x >> 6;
    const int d = threadIdx.x & 63;
    const int row = blockIdx.x * 4 + g;
    const int t = row % L;
    lp[g][d]  = (t == 0) ? 0.0f : allL[(row - 1) * 64 + d];
    its[g][d] = it_embed[(size_t)it_data[row] * 64 + d];
    ln[g][d]  = allL[row * 64 + d];
    const int e = e_data[row];
    ee[g][d]      = e_embed[(size_t)e * DE + d];
    ee[g][64 + d] = e_embed[(size_t)e * DE + 64 + d];
    __syncthreads();
    float g2 = b2[d], g3 = b3[d], g4 = b4[d], py = b5[d];
    #pragma unroll 4
    for (int k = 0; k < 64; ++k) {
        const float l0 = lp[g][k], i0 = its[g][k], n0 = ln[g][k];
        g2 += W2T[k * 64 + d] * l0 + W2T[(64 + k) * 64 + d] * i0 + W2T[(128 + k) * 64 + d] * n0;
        g3 += W3T[k * 64 + d] * l0 + W3T[(64 + k) * 64 + d] * i0 + W3T[(128 + k) * 64 + d] * n0;
        g4 += W4T[(128 + k) * 64 + d] * i0;
        py += W5T[k * 64 + d] * ee[g][k] + W5T[(64 + k) * 64 + d] * ee[g][64 + k];
    }
    G2[row * 64 + d]   = g2;
    G3[row * 64 + d]   = g3;
    G4it[row * 64 + d] = g4;
    prey[row * 64 + d] = py;
}

// ---------------- persistent recurrence: all 99 steps -----------------------
// grid (B, 8): b = blockIdx.x, cx = blockIdx.y (s-chunk of 64 rows). 256 thr.
// PLAIN launch (not cooperative): 90KB LDS -> hard 1 block/CU, 256 blocks on
// 256 CUs -> all blocks necessarily co-resident; spin cannot deadlock.
// Cross-block h_tilde exchange: single-writer publish (tid 0 stores all 64
// partials, release fence, counter RMW); every consumer thread spins + agent
// acquire fence before loading partials.
__global__ __launch_bounds__(256, 1) void k_steps(
    float* __restrict__ htb, unsigned* __restrict__ cnt,
    const float* __restrict__ G2, const float* __restrict__ G3,
    const float* __restrict__ G4it,
    const float* __restrict__ W2T, const float* __restrict__ W3T,
    const float* __restrict__ W4T,
    const float* __restrict__ q_matrix, const int* __restrict__ e_data,
    const float* __restrict__ h0)
{
    __shared__ float hS[64][68];      // h rows, padded
    __shared__ float waS[64][64];     // W4a, k-major
    __shared__ float wbS[64][64];     // W4b, k-major
    __shared__ float w2S[64][64];     // W2 h_tilde-part, k-major
    __shared__ float w3S[64][64];     // W3 h_tilde-part, k-major
    __shared__ float HTP[64], LGs[64], Vs[64], qeS[64], qnS[64], outS[64];
    __shared__ float sred[4][64], s2red[4][64], s3red[4][64], wred[4][64];

    const int tid = threadIdx.x;
    const int b  = blockIdx.x;
    const int cx = blockIdx.y;
    const int d  = tid & 63;
    const int kg = tid >> 6;
    const int r0 = cx * 64;
    const int rt = tid >> 4;
    const int dt = tid & 15;

    // one-time staging
    for (int i = tid; i < 4096; i += 256) {
        const int k = i >> 6, dd = i & 63;
        waS[k][dd] = W4T[i];
        wbS[k][dd] = W4T[64 * 64 + i];
        w2S[k][dd] = W2T[192 * 64 + i];
        w3S[k][dd] = W3T[192 * 64 + i];
    }
    for (int i = tid; i < 4096; i += 256) {
        const int r = i >> 6, dd = i & 63, gr = r0 + r;
        hS[r][dd] = (gr < S) ? h0[gr * 64 + dd] : 0.0f;
    }
    __syncthreads();

    // initial h_tilde partial: q[e_0] . h0 over this chunk
    if (tid < 64) {
        const int gr = r0 + tid;
        qnS[tid] = (gr < S) ? q_matrix[(size_t)e_data[b * L] * S + gr] : 0.0f;
    }
    __syncthreads();
    if (tid < 64) {
        float s = 0.0f;
        #pragma unroll 8
        for (int r = 0; r < 64; ++r) s += qnS[r] * hS[r][tid];
        outS[tid] = s;
    }
    __syncthreads();
    if (tid == 0) {
        float* dst = &htb[((size_t)0 * B + b) * 512 + (size_t)cx * 64];
        #pragma unroll
        for (int i = 0; i < 64; ++i)
            __hip_atomic_store(&dst[i], outS[i], __ATOMIC_RELAXED, __HIP_MEMORY_SCOPE_AGENT);
        __builtin_amdgcn_fence(__ATOMIC_RELEASE, "agent");
        __hip_atomic_fetch_add(&cnt[b], 1u, __ATOMIC_RELAXED, __HIP_MEMORY_SCOPE_AGENT);
    }

    for (int t = 0; t < L - 1; ++t) {
        // 1) big GEMM: acc = h_chunk(64x64) @ W4a^T — independent of h_tilde,
        //    so it runs BEFORE the sync wait and hides inter-block skew.
        float acc[4][4];
        #pragma unroll
        for (int j = 0; j < 4; ++j) { acc[j][0] = 0.f; acc[j][1] = 0.f; acc[j][2] = 0.f; acc[j][3] = 0.f; }
        #pragma unroll
        for (int k4 = 0; k4 < 16; ++k4) {
            float4 hv[4], wv[4];
            #pragma unroll
            for (int j = 0; j < 4; ++j) hv[j] = *(const float4*)&hS[rt * 4 + j][k4 * 4];
            #pragma unroll
            for (int j = 0; j < 4; ++j) wv[j] = *(const float4*)&waS[k4 * 4 + j][dt * 4];
            #pragma unroll
            for (int j = 0; j < 4; ++j) {
                const float a0 = hv[j].x, a1 = hv[j].y, a2 = hv[j].z, a3 = hv[j].w;
                acc[j][0] += a0 * wv[0].x + a1 * wv[1].x + a2 * wv[2].x + a3 * wv[3].x;
                acc[j][1] += a0 * wv[0].y + a1 * wv[1].y + a2 * wv[2].y + a3 * wv[3].y;
                acc[j][2] += a0 * wv[0].z + a1 * wv[1].z + a2 * wv[2].z + a3 * wv[3].z;
                acc[j][3] += a0 * wv[0].w + a1 * wv[1].w + a2 * wv[2].w + a3 * wv[3].w;
            }
        }

        // 2) wait for all 8 partials of h_tilde_t — EVERY thread spins and
        //    acquires, so each thread's subsequent loads are ordered.
        {
            const unsigned want = 8u * (unsigned)(t + 1);
            unsigned guard = 0;
            while (__hip_atomic_load(&cnt[b], __ATOMIC_RELAXED, __HIP_MEMORY_SCOPE_AGENT) < want) {
                if (++guard > (1u << 22)) break;
                __builtin_amdgcn_s_sleep(2);
            }
            __builtin_amdgcn_fence(__ATOMIC_ACQUIRE, "agent");
        }

        // 3) load partials + per-step inputs
        const float* hp_base = &htb[((size_t)t * B + b) * 512];
        const float p0 = __hip_atomic_load(hp_base + (2 * kg) * 64 + d,
                                           __ATOMIC_RELAXED, __HIP_MEMORY_SCOPE_AGENT);
        const float p1 = __hip_atomic_load(hp_base + (2 * kg + 1) * 64 + d,
                                           __ATOMIC_RELAXED, __HIP_MEMORY_SCOPE_AGENT);
        float qe = 0.0f, qn = 0.0f, g2v = 0.0f, g3v = 0.0f, g4v = 0.0f;
        if (tid < 64) {
            const int et = e_data[b * L + t];
            const int en = e_data[b * L + t + 1];
            const int gr = r0 + tid;
            if (gr < S) {
                qe = q_matrix[(size_t)et * S + gr];
                qn = q_matrix[(size_t)en * S + gr];
            }
            g2v = G2[(b * L + t) * 64 + d];
            g3v = G3[(b * L + t) * 64 + d];
            g4v = G4it[(b * L + t) * 64 + d];
        }
        sred[kg][d] = p0 + p1;
        if (tid < 64) { qeS[d] = qe; qnS[d] = qn; }
        __syncthreads();
        if (tid < 64) HTP[d] = sred[0][d] + sred[1][d] + sred[2][d] + sred[3][d];
        __syncthreads();
        {
            float a2 = 0.f, a3 = 0.f;
            #pragma unroll
            for (int kk = 0; kk < 16; ++kk) {
                const int k = kg * 16 + kk;
                const float hp = HTP[k];
                a2 += w2S[k][d] * hp;
                a3 += w3S[k][d] * hp;
            }
            s2red[kg][d] = a2; s3red[kg][d] = a3;
        }
        __syncthreads();
        if (tid < 64) {
            const float g2 = g2v + s2red[0][d] + s2red[1][d] + s2red[2][d] + s2red[3][d];
            const float g3 = g3v + s3red[0][d] + s3red[1][d] + s3red[2][d] + s3red[3][d];
            LGs[d] = sigm(g3) * (tanhf(g2) + 1.0f) * 0.5f;
        }
        __syncthreads();
        {
            float a = 0.f;
            #pragma unroll
            for (int kk = 0; kk < 16; ++kk) {
                const int k = kg * 16 + kk;
                a += wbS[k][d] * LGs[k];
            }
            sred[kg][d] = a;
        }
        __syncthreads();
        if (tid < 64) Vs[d] = g4v + sred[0][d] + sred[1][d] + sred[2][d] + sred[3][d];
        __syncthreads();

        // 4) epilogue: h = qe*LG + sigmoid(acc + V)*h_old; partial qn.h_new
        float part[4] = {0.f, 0.f, 0.f, 0.f};
        const float lg0 = LGs[dt * 4], lg1 = LGs[dt * 4 + 1], lg2 = LGs[dt * 4 + 2], lg3 = LGs[dt * 4 + 3];
        const float v0 = Vs[dt * 4], v1 = Vs[dt * 4 + 1], v2 = Vs[dt * 4 + 2], v3 = Vs[dt * 4 + 3];
        #pragma unroll
        for (int j = 0; j < 4; ++j) {
            const int r = rt * 4 + j;
            const float qer = qeS[r], qnr = qnS[r];
            const float4 hold = *(const float4*)&hS[r][dt * 4];
            const float hn0 = qer * lg0 + sigm(acc[j][0] + v0) * hold.x;
            const float hn1 = qer * lg1 + sigm(acc[j][1] + v1) * hold.y;
            const float hn2 = qer * lg2 + sigm(acc[j][2] + v2) * hold.z;
            const float hn3 = qer * lg3 + sigm(acc[j][3] + v3) * hold.w;
            hS[r][dt * 4]     = hn0;
            hS[r][dt * 4 + 1] = hn1;
            hS[r][dt * 4 + 2] = hn2;
            hS[r][dt * 4 + 3] = hn3;
            part[0] += qnr * hn0; part[1] += qnr * hn1;
            part[2] += qnr * hn2; part[3] += qnr * hn3;
        }
        #pragma unroll
        for (int i = 0; i < 4; ++i) {
            float v = part[i];
            v += __shfl_xor(v, 16);
            v += __shfl_xor(v, 32);
            part[i] = v;
        }
        const int wid = tid >> 6, lane = tid & 63;
        if (lane < 16) {
            #pragma unroll
            for (int i = 0; i < 4; ++i) wred[wid][lane * 4 + i] = part[i];
        }
        __syncthreads();
        if (tid < 64) outS[d] = wred[0][d] + wred[1][d] + wred[2][d] + wred[3][d];
        __syncthreads();

        // 5) single-writer publish of this chunk's h_tilde_{t+1} partial
        if (tid == 0) {
            float* dst = &htb[((size_t)(t + 1) * B + b) * 512 + (size_t)cx * 64];
            #pragma unroll
            for (int i = 0; i < 64; ++i)
                __hip_atomic_store(&dst[i], outS[i], __ATOMIC_RELAXED, __HIP_MEMORY_SCOPE_AGENT);
            __builtin_amdgcn_fence(__ATOMIC_RELEASE, "agent");
            __hip_atomic_fetch_add(&cnt[b], 1u, __ATOMIC_RELAXED, __HIP_MEMORY_SCOPE_AGENT);
        }
    }
}

// ---------------- epilogue: y_t for t=1..99 --------------------------------
__global__ __launch_bounds__(64) void k_y(
    const float* __restrict__ htb, const float* __restrict__ prey,
    const float* __restrict__ W5T, float* __restrict__ pred)
{
    __shared__ float HT[64];
    const int j = blockIdx.x + 1;    // 1..99
    const int b = blockIdx.y;
    const int d = threadIdx.x;
    float s = 0.0f;
    #pragma unroll
    for (int c = 0; c < 8; ++c)
        s += htb[((size_t)j * B + b) * 512 + c * 64 + d];
    HT[d] = s;
    __syncthreads();
    float acc = prey[(b * L + j) * 64 + d];
    #pragma unroll 8
    for (int k = 0; k < 64; ++k) acc += W5T[(128 + k) * 64 + d] * HT[k];
    float y = sigm(acc);
    #pragma unroll
    for (int m = 1; m < 64; m <<= 1) y += __shfl_xor(y, m);
    if (d == 0) pred[b * L + j] = y * (1.0f / 64.0f);
}

} // namespace

extern "C" void kernel_launch(void* const* d_in, const int* in_sizes, int n_in,
                              void* d_out, int out_size, void* d_ws, size_t ws_size,
                              hipStream_t stream)
{
    const int*   e_data   = (const int*)d_in[0];
    const int*   a_data   = (const int*)d_in[1];
    const int*   at_data  = (const int*)d_in[2];
    const int*   it_data  = (const int*)d_in[3];
    const float* q_matrix = (const float*)d_in[4];
    const float* h0       = (const float*)d_in[5];
    const float* e_embed  = (const float*)d_in[6];
    const float* at_embed = (const float*)d_in[7];
    const float* it_embed = (const float*)d_in[8];
    const float* W1 = (const float*)d_in[9];  const float* b1 = (const float*)d_in[10];
    const float* W2 = (const float*)d_in[11]; const float* b2 = (const float*)d_in[12];
    const float* W3 = (const float*)d_in[13]; const float* b3 = (const float*)d_in[14];
    const float* W4 = (const float*)d_in[15]; const float* b4 = (const float*)d_in[16];
    const float* W5 = (const float*)d_in[17]; const float* b5 = (const float*)d_in[18];
    float* pred = (float*)d_out;

    float* ws = (float*)d_ws;
    float* W1T  = ws;                         // 256*64 = 16384
    float* W2T  = W1T  + 16384;
    float* W3T  = W2T  + 16384;
    float* W4T  = W3T  + 16384;               // 192*64 = 12288
    float* W5T  = W4T  + 12288;
    float* allL = W5T  + 12288;               // B*L*64 = 204800
    float* G2   = allL + 204800;
    float* G3   = G2   + 204800;
    float* G4it = G3   + 204800;
    float* prey = G4it + 204800;
    float* htb  = prey + 204800;              // L*B*512 = 1638400
    unsigned* cnt = (unsigned*)(htb + 1638400);   // B counters
    // total ~10.9 MB

    hipLaunchKernelGGL(k_init, dim3(64), dim3(256), 0, stream,
                       W1, W2, W3, W4, W5, W1T, W2T, W3T, W4T, W5T, cnt, pred);
    hipLaunchKernelGGL(k_all_learning, dim3(B * L / 4), dim3(256), 0, stream,
                       e_data, a_data, at_data, e_embed, at_embed, W1T, b1, allL);
    hipLaunchKernelGGL(k_pre, dim3(B * L / 4), dim3(256), 0, stream,
                       e_data, it_data, e_embed, it_embed, allL,
                       W2T, W3T, W4T, W5T, b2, b3, b4, b5, G2, G3, G4it, prey);
    hipLaunchKernelGGL(k_steps, dim3(B, 8), dim3(256), 0, stream,
                       htb, cnt, G2, G3, G4it, W2T, W3T, W4T,
                       q_matrix, e_data, h0);
    hipLaunchKernelGGL(k_y, dim3(L - 1, B), dim3(64), 0, stream,
                       htb, prey, W5T, pred);
}

// Round 6
// 1218.521 us; speedup vs baseline: 2.4881x; 2.4881x over previous
//
#include <hip/hip_runtime.h>
#include <hip/hip_bf16.h>

namespace {

constexpr int B  = 32;
constexpr int L  = 100;
constexpr int S  = 501;
constexpr int DK = 64;
constexpr int DE = 128;

__device__ __forceinline__ float sigm(float x) {
    return __fdividef(1.0f, 1.0f + __expf(-x));
}

// ---------------- init: transpose weights (k-major), zero counters, pred[:,0]
__global__ __launch_bounds__(256) void k_init(
    const float* __restrict__ W1, const float* __restrict__ W2,
    const float* __restrict__ W3, const float* __restrict__ W4,
    const float* __restrict__ W5,
    float* __restrict__ W1T, float* __restrict__ W2T, float* __restrict__ W3T,
    float* __restrict__ W4T, float* __restrict__ W5T,
    unsigned* __restrict__ cnt, float* __restrict__ pred)
{
    const int idx = blockIdx.x * 256 + threadIdx.x;
    const int st  = gridDim.x * 256;
    for (int i = idx; i < 64 * 256; i += st) {
        int dd = i >> 8, kk = i & 255;
        W1T[kk * 64 + dd] = W1[i];
        W2T[kk * 64 + dd] = W2[i];
        W3T[kk * 64 + dd] = W3[i];
    }
    for (int i = idx; i < 64 * 192; i += st) {
        int dd = i / 192, kk = i % 192;
        W4T[kk * 64 + dd] = W4[i];
        W5T[kk * 64 + dd] = W5[i];
    }
    if (idx < B) { cnt[idx] = 0u; pred[idx * L] = 0.0f; }
}

// ---------------- all_learning = concat(e,at,a) @ W1^T + b1 ----------------
__global__ __launch_bounds__(256) void k_all_learning(
    const int* __restrict__ e_data, const int* __restrict__ a_data,
    const int* __restrict__ at_data,
    const float* __restrict__ e_embed, const float* __restrict__ at_embed,
    const float* __restrict__ W1T, const float* __restrict__ b1,
    float* __restrict__ allL)
{
    __shared__ float in_s[4][257];
    const int g = threadIdx.x >> 6;
    const int d = threadIdx.x & 63;
    const int row = blockIdx.x * 4 + g;
    const int e  = e_data[row];
    const int at = at_data[row];
    in_s[g][d]       = e_embed[(size_t)e * DE + d];
    in_s[g][64 + d]  = e_embed[(size_t)e * DE + 64 + d];
    in_s[g][128 + d] = at_embed[(size_t)at * DK + d];
    in_s[g][192 + d] = (float)a_data[row];
    __syncthreads();
    float acc = b1[d];
    #pragma unroll 8
    for (int k = 0; k < 256; ++k) acc += W1T[k * 64 + d] * in_s[g][k];
    allL[row * DK + d] = acc;
}

// ---------------- G2,G3 (non-recurrent parts), G4it, prey ------------------
__global__ __launch_bounds__(256) void k_pre(
    const int* __restrict__ e_data, const int* __restrict__ it_data,
    const float* __restrict__ e_embed, const float* __restrict__ it_embed,
    const float* __restrict__ allL,
    const float* __restrict__ W2T, const float* __restrict__ W3T,
    const float* __restrict__ W4T, const float* __restrict__ W5T,
    const float* __restrict__ b2, const float* __restrict__ b3,
    const float* __restrict__ b4, const float* __restrict__ b5,
    float* __restrict__ G2, float* __restrict__ G3,
    float* __restrict__ G4it, float* __restrict__ prey)
{
    __shared__ float lp[4][64], its[4][64], ln[4][64], ee[4][128];
    const int g = threadIdx.x >> 6;
    const int d = threadIdx.x & 63;
    const int row = blockIdx.x * 4 + g;
    const int t = row % L;
    lp[g][d]  = (t == 0) ? 0.0f : allL[(row - 1) * 64 + d];
    its[g][d] = it_embed[(size_t)it_data[row] * 64 + d];
    ln[g][d]  = allL[row * 64 + d];
    const int e = e_data[row];
    ee[g][d]      = e_embed[(size_t)e * DE + d];
    ee[g][64 + d] = e_embed[(size_t)e * DE + 64 + d];
    __syncthreads();
    float g2 = b2[d], g3 = b3[d], g4 = b4[d], py = b5[d];
    #pragma unroll 4
    for (int k = 0; k < 64; ++k) {
        const float l0 = lp[g][k], i0 = its[g][k], n0 = ln[g][k];
        g2 += W2T[k * 64 + d] * l0 + W2T[(64 + k) * 64 + d] * i0 + W2T[(128 + k) * 64 + d] * n0;
        g3 += W3T[k * 64 + d] * l0 + W3T[(64 + k) * 64 + d] * i0 + W3T[(128 + k) * 64 + d] * n0;
        g4 += W4T[(128 + k) * 64 + d] * i0;
        py += W5T[k * 64 + d] * ee[g][k] + W5T[(64 + k) * 64 + d] * ee[g][64 + k];
    }
    G2[row * 64 + d]   = g2;
    G3[row * 64 + d]   = g3;
    G4it[row * 64 + d] = g4;
    prey[row * 64 + d] = py;
}

// ---------------- persistent recurrence: all 99 steps -----------------------
// grid (B, 8): b = blockIdx.x, cx = blockIdx.y (s-chunk of 64 rows). 256 thr.
// PLAIN launch; 88KB LDS -> 1 block/CU, 256 blocks on 256 CUs -> co-resident.
// Cross-block h_tilde exchange with NO FENCES: all cross-block data moves via
// relaxed AGENT-scope atomics (sc1, cache-bypassing -> LLC coherence point).
// Ordering: __syncthreads() drains vmcnt(0) per wave before the barrier, so
// all 64 lanes' publishes are at the LLC before tid0 bumps the counter.
// This avoids the buffer_wbl2 / buffer_inv L2 storms that agent fences cost
// (round 5: 971 MB writeback traffic, 31.6 us/step).
__global__ __launch_bounds__(256, 1) void k_steps(
    float* __restrict__ htb, unsigned* __restrict__ cnt,
    const float* __restrict__ G2, const float* __restrict__ G3,
    const float* __restrict__ G4it,
    const float* __restrict__ W2T, const float* __restrict__ W3T,
    const float* __restrict__ W4T,
    const float* __restrict__ q_matrix, const int* __restrict__ e_data,
    const float* __restrict__ h0)
{
    __shared__ float hS[64][68];      // h rows, padded
    __shared__ float waS[64][64];     // W4a, k-major
    __shared__ float wbS[64][64];     // W4b, k-major
    __shared__ float w2S[64][64];     // W2 h_tilde-part, k-major
    __shared__ float w3S[64][64];     // W3 h_tilde-part, k-major
    __shared__ float HTP[64], LGs[64], Vs[64], qeS[64], qnS[64];
    __shared__ float sred[4][64], s2red[4][64], s3red[4][64], wred[4][64];

    const int tid = threadIdx.x;
    const int b  = blockIdx.x;
    const int cx = blockIdx.y;
    const int d  = tid & 63;
    const int kg = tid >> 6;
    const int r0 = cx * 64;
    const int rt = tid >> 4;
    const int dt = tid & 15;

    // one-time staging
    for (int i = tid; i < 4096; i += 256) {
        const int k = i >> 6, dd = i & 63;
        waS[k][dd] = W4T[i];
        wbS[k][dd] = W4T[64 * 64 + i];
        w2S[k][dd] = W2T[192 * 64 + i];
        w3S[k][dd] = W3T[192 * 64 + i];
    }
    for (int i = tid; i < 4096; i += 256) {
        const int r = i >> 6, dd = i & 63, gr = r0 + r;
        hS[r][dd] = (gr < S) ? h0[gr * 64 + dd] : 0.0f;
    }
    __syncthreads();

    // initial h_tilde partial: q[e_0] . h0 over this chunk
    if (tid < 64) {
        const int gr = r0 + tid;
        qnS[tid] = (gr < S) ? q_matrix[(size_t)e_data[b * L] * S + gr] : 0.0f;
    }
    __syncthreads();
    if (tid < 64) {
        float s = 0.0f;
        #pragma unroll 8
        for (int r = 0; r < 64; ++r) s += qnS[r] * hS[r][tid];
        __hip_atomic_store(&htb[((size_t)0 * B + b) * 512 + (size_t)cx * 64 + tid], s,
                           __ATOMIC_RELAXED, __HIP_MEMORY_SCOPE_AGENT);
    }
    __syncthreads();   // drains vmcnt(0): publishes are at the LLC
    if (tid == 0)
        __hip_atomic_fetch_add(&cnt[b], 1u, __ATOMIC_RELAXED, __HIP_MEMORY_SCOPE_AGENT);

    for (int t = 0; t < L - 1; ++t) {
        // 0) h_tilde-independent per-step loads, issued early (hide under GEMM)
        float qe = 0.0f, qn = 0.0f, g2v = 0.0f, g3v = 0.0f, g4v = 0.0f;
        if (tid < 64) {
            const int et = e_data[b * L + t];
            const int en = e_data[b * L + t + 1];
            const int gr = r0 + tid;
            if (gr < S) {
                qe = q_matrix[(size_t)et * S + gr];
                qn = q_matrix[(size_t)en * S + gr];
            }
            g2v = G2[(b * L + t) * 64 + d];
            g3v = G3[(b * L + t) * 64 + d];
            g4v = G4it[(b * L + t) * 64 + d];
        }

        // 1) big GEMM: acc = h_chunk(64x64) @ W4a^T — independent of h_tilde,
        //    runs BEFORE the sync wait to hide inter-block skew.
        float acc[4][4];
        #pragma unroll
        for (int j = 0; j < 4; ++j) { acc[j][0] = 0.f; acc[j][1] = 0.f; acc[j][2] = 0.f; acc[j][3] = 0.f; }
        #pragma unroll
        for (int k4 = 0; k4 < 16; ++k4) {
            float4 hv[4], wv[4];
            #pragma unroll
            for (int j = 0; j < 4; ++j) hv[j] = *(const float4*)&hS[rt * 4 + j][k4 * 4];
            #pragma unroll
            for (int j = 0; j < 4; ++j) wv[j] = *(const float4*)&waS[k4 * 4 + j][dt * 4];
            #pragma unroll
            for (int j = 0; j < 4; ++j) {
                const float a0 = hv[j].x, a1 = hv[j].y, a2 = hv[j].z, a3 = hv[j].w;
                acc[j][0] += a0 * wv[0].x + a1 * wv[1].x + a2 * wv[2].x + a3 * wv[3].x;
                acc[j][1] += a0 * wv[0].y + a1 * wv[1].y + a2 * wv[2].y + a3 * wv[3].y;
                acc[j][2] += a0 * wv[0].z + a1 * wv[1].z + a2 * wv[2].z + a3 * wv[3].z;
                acc[j][3] += a0 * wv[0].w + a1 * wv[1].w + a2 * wv[2].w + a3 * wv[3].w;
            }
        }

        // 2) wait for all 8 partials of h_tilde_t: ONE poller + barrier.
        if (tid == 0) {
            const unsigned want = 8u * (unsigned)(t + 1);
            unsigned guard = 0;
            while (__hip_atomic_load(&cnt[b], __ATOMIC_RELAXED, __HIP_MEMORY_SCOPE_AGENT) < want) {
                if (++guard > (1u << 24)) break;
                __builtin_amdgcn_s_sleep(1);
            }
        }
        __syncthreads();
        asm volatile("" ::: "memory");   // compiler ordering hygiene

        // 3) load partials (sc1 -> fresh LLC data), finish h_tilde reduce
        const float* hp_base = &htb[((size_t)t * B + b) * 512];
        const float p0 = __hip_atomic_load(hp_base + (2 * kg) * 64 + d,
                                           __ATOMIC_RELAXED, __HIP_MEMORY_SCOPE_AGENT);
        const float p1 = __hip_atomic_load(hp_base + (2 * kg + 1) * 64 + d,
                                           __ATOMIC_RELAXED, __HIP_MEMORY_SCOPE_AGENT);
        sred[kg][d] = p0 + p1;
        if (tid < 64) { qeS[d] = qe; qnS[d] = qn; }
        __syncthreads();
        if (tid < 64) HTP[d] = sred[0][d] + sred[1][d] + sred[2][d] + sred[3][d];
        __syncthreads();
        {
            float a2 = 0.f, a3 = 0.f;
            #pragma unroll
            for (int kk = 0; kk < 16; ++kk) {
                const int k = kg * 16 + kk;
                const float hp = HTP[k];
                a2 += w2S[k][d] * hp;
                a3 += w3S[k][d] * hp;
            }
            s2red[kg][d] = a2; s3red[kg][d] = a3;
        }
        __syncthreads();
        if (tid < 64) {
            const float g2 = g2v + s2red[0][d] + s2red[1][d] + s2red[2][d] + s2red[3][d];
            const float g3 = g3v + s3red[0][d] + s3red[1][d] + s3red[2][d] + s3red[3][d];
            LGs[d] = sigm(g3) * (tanhf(g2) + 1.0f) * 0.5f;
        }
        __syncthreads();
        {
            float a = 0.f;
            #pragma unroll
            for (int kk = 0; kk < 16; ++kk) {
                const int k = kg * 16 + kk;
                a += wbS[k][d] * LGs[k];
            }
            sred[kg][d] = a;
        }
        __syncthreads();
        if (tid < 64) Vs[d] = g4v + sred[0][d] + sred[1][d] + sred[2][d] + sred[3][d];
        __syncthreads();

        // 4) epilogue: h = qe*LG + sigmoid(acc + V)*h_old; partial qn.h_new
        float part[4] = {0.f, 0.f, 0.f, 0.f};
        const float lg0 = LGs[dt * 4], lg1 = LGs[dt * 4 + 1], lg2 = LGs[dt * 4 + 2], lg3 = LGs[dt * 4 + 3];
        const float v0 = Vs[dt * 4], v1 = Vs[dt * 4 + 1], v2 = Vs[dt * 4 + 2], v3 = Vs[dt * 4 + 3];
        #pragma unroll
        for (int j = 0; j < 4; ++j) {
            const int r = rt * 4 + j;
            const float qer = qeS[r], qnr = qnS[r];
            const float4 hold = *(const float4*)&hS[r][dt * 4];
            const float hn0 = qer * lg0 + sigm(acc[j][0] + v0) * hold.x;
            const float hn1 = qer * lg1 + sigm(acc[j][1] + v1) * hold.y;
            const float hn2 = qer * lg2 + sigm(acc[j][2] + v2) * hold.z;
            const float hn3 = qer * lg3 + sigm(acc[j][3] + v3) * hold.w;
            hS[r][dt * 4]     = hn0;
            hS[r][dt * 4 + 1] = hn1;
            hS[r][dt * 4 + 2] = hn2;
            hS[r][dt * 4 + 3] = hn3;
            part[0] += qnr * hn0; part[1] += qnr * hn1;
            part[2] += qnr * hn2; part[3] += qnr * hn3;
        }
        #pragma unroll
        for (int i = 0; i < 4; ++i) {
            float v = part[i];
            v += __shfl_xor(v, 16);
            v += __shfl_xor(v, 32);
            part[i] = v;
        }
        const int wid = tid >> 6, lane = tid & 63;
        if (lane < 16) {
            #pragma unroll
            for (int i = 0; i < 4; ++i) wred[wid][lane * 4 + i] = part[i];
        }
        __syncthreads();

        // 5) publish this chunk's h_tilde_{t+1} partial: 64 parallel sc1
        //    stores, barrier (vmcnt drain), then counter bump.
        if (tid < 64) {
            const float s = wred[0][d] + wred[1][d] + wred[2][d] + wred[3][d];
            __hip_atomic_store(&htb[((size_t)(t + 1) * B + b) * 512 + (size_t)cx * 64 + d], s,
                               __ATOMIC_RELAXED, __HIP_MEMORY_SCOPE_AGENT);
        }
        __syncthreads();
        if (tid == 0)
            __hip_atomic_fetch_add(&cnt[b], 1u, __ATOMIC_RELAXED, __HIP_MEMORY_SCOPE_AGENT);
    }
}

// ---------------- epilogue: y_t for t=1..99 --------------------------------
__global__ __launch_bounds__(64) void k_y(
    const float* __restrict__ htb, const float* __restrict__ prey,
    const float* __restrict__ W5T, float* __restrict__ pred)
{
    __shared__ float HT[64];
    const int j = blockIdx.x + 1;    // 1..99
    const int b = blockIdx.y;
    const int d = threadIdx.x;
    float s = 0.0f;
    #pragma unroll
    for (int c = 0; c < 8; ++c)
        s += htb[((size_t)j * B + b) * 512 + c * 64 + d];
    HT[d] = s;
    __syncthreads();
    float acc = prey[(b * L + j) * 64 + d];
    #pragma unroll 8
    for (int k = 0; k < 64; ++k) acc += W5T[(128 + k) * 64 + d] * HT[k];
    float y = sigm(acc);
    #pragma unroll
    for (int m = 1; m < 64; m <<= 1) y += __shfl_xor(y, m);
    if (d == 0) pred[b * L + j] = y * (1.0f / 64.0f);
}

} // namespace

extern "C" void kernel_launch(void* const* d_in, const int* in_sizes, int n_in,
                              void* d_out, int out_size, void* d_ws, size_t ws_size,
                              hipStream_t stream)
{
    const int*   e_data   = (const int*)d_in[0];
    const int*   a_data   = (const int*)d_in[1];
    const int*   at_data  = (const int*)d_in[2];
    const int*   it_data  = (const int*)d_in[3];
    const float* q_matrix = (const float*)d_in[4];
    const float* h0       = (const float*)d_in[5];
    const float* e_embed  = (const float*)d_in[6];
    const float* at_embed = (const float*)d_in[7];
    const float* it_embed = (const float*)d_in[8];
    const float* W1 = (const float*)d_in[9];  const float* b1 = (const float*)d_in[10];
    const float* W2 = (const float*)d_in[11]; const float* b2 = (const float*)d_in[12];
    const float* W3 = (const float*)d_in[13]; const float* b3 = (const float*)d_in[14];
    const float* W4 = (const float*)d_in[15]; const float* b4 = (const float*)d_in[16];
    const float* W5 = (const float*)d_in[17]; const float* b5 = (const float*)d_in[18];
    float* pred = (float*)d_out;

    float* ws = (float*)d_ws;
    float* W1T  = ws;                         // 256*64 = 16384
    float* W2T  = W1T  + 16384;
    float* W3T  = W2T  + 16384;
    float* W4T  = W3T  + 16384;               // 192*64 = 12288
    float* W5T  = W4T  + 12288;
    float* allL = W5T  + 12288;               // B*L*64 = 204800
    float* G2   = allL + 204800;
    float* G3   = G2   + 204800;
    float* G4it = G3   + 204800;
    float* prey = G4it + 204800;
    float* htb  = prey + 204800;              // L*B*512 = 1638400
    unsigned* cnt = (unsigned*)(htb + 1638400);   // B counters
    // total ~10.9 MB

    hipLaunchKernelGGL(k_init, dim3(64), dim3(256), 0, stream,
                       W1, W2, W3, W4, W5, W1T, W2T, W3T, W4T, W5T, cnt, pred);
    hipLaunchKernelGGL(k_all_learning, dim3(B * L / 4), dim3(256), 0, stream,
                       e_data, a_data, at_data, e_embed, at_embed, W1T, b1, allL);
    hipLaunchKernelGGL(k_pre, dim3(B * L / 4), dim3(256), 0, stream,
                       e_data, it_data, e_embed, it_embed, allL,
                       W2T, W3T, W4T, W5T, b2, b3, b4, b5, G2, G3, G4it, prey);
    hipLaunchKernelGGL(k_steps, dim3(B, 8), dim3(256), 0, stream,
                       htb, cnt, G2, G3, G4it, W2T, W3T, W4T,
                       q_matrix, e_data, h0);
    hipLaunchKernelGGL(k_y, dim3(L - 1, B), dim3(64), 0, stream,
                       htb, prey, W5T, pred);
}

// Round 7
// 1052.866 us; speedup vs baseline: 2.8795x; 1.1573x over previous
//
#include <hip/hip_runtime.h>
#include <hip/hip_bf16.h>

namespace {

constexpr int B  = 32;
constexpr int L  = 100;
constexpr int S  = 501;
constexpr int DK = 64;
constexpr int DE = 128;

__device__ __forceinline__ float sigm(float x) {
    return __fdividef(1.0f, 1.0f + __expf(-x));
}

// ---------------- init: transpose weights (k-major), zero counters, pred[:,0]
__global__ __launch_bounds__(256) void k_init(
    const float* __restrict__ W1, const float* __restrict__ W2,
    const float* __restrict__ W3, const float* __restrict__ W4,
    const float* __restrict__ W5,
    float* __restrict__ W1T, float* __restrict__ W2T, float* __restrict__ W3T,
    float* __restrict__ W4T, float* __restrict__ W5T,
    unsigned* __restrict__ cnt, float* __restrict__ pred)
{
    const int idx = blockIdx.x * 256 + threadIdx.x;
    const int st  = gridDim.x * 256;
    for (int i = idx; i < 64 * 256; i += st) {
        int dd = i >> 8, kk = i & 255;
        W1T[kk * 64 + dd] = W1[i];
        W2T[kk * 64 + dd] = W2[i];
        W3T[kk * 64 + dd] = W3[i];
    }
    for (int i = idx; i < 64 * 192; i += st) {
        int dd = i / 192, kk = i % 192;
        W4T[kk * 64 + dd] = W4[i];
        W5T[kk * 64 + dd] = W5[i];
    }
    if (idx < 1024) cnt[idx] = 0u;          // padded: 1 counter per 128B
    if (idx < B) pred[idx * L] = 0.0f;
}

// ---------------- all_learning = concat(e,at,a) @ W1^T + b1 ----------------
__global__ __launch_bounds__(256) void k_all_learning(
    const int* __restrict__ e_data, const int* __restrict__ a_data,
    const int* __restrict__ at_data,
    const float* __restrict__ e_embed, const float* __restrict__ at_embed,
    const float* __restrict__ W1T, const float* __restrict__ b1,
    float* __restrict__ allL)
{
    __shared__ float in_s[4][257];
    const int g = threadIdx.x >> 6;
    const int d = threadIdx.x & 63;
    const int row = blockIdx.x * 4 + g;
    const int e  = e_data[row];
    const int at = at_data[row];
    in_s[g][d]       = e_embed[(size_t)e * DE + d];
    in_s[g][64 + d]  = e_embed[(size_t)e * DE + 64 + d];
    in_s[g][128 + d] = at_embed[(size_t)at * DK + d];
    in_s[g][192 + d] = (float)a_data[row];
    __syncthreads();
    float acc = b1[d];
    #pragma unroll 8
    for (int k = 0; k < 256; ++k) acc += W1T[k * 64 + d] * in_s[g][k];
    allL[row * DK + d] = acc;
}

// ---------------- G2,G3 (non-recurrent parts), G4it, prey ------------------
__global__ __launch_bounds__(256) void k_pre(
    const int* __restrict__ e_data, const int* __restrict__ it_data,
    const float* __restrict__ e_embed, const float* __restrict__ it_embed,
    const float* __restrict__ allL,
    const float* __restrict__ W2T, const float* __restrict__ W3T,
    const float* __restrict__ W4T, const float* __restrict__ W5T,
    const float* __restrict__ b2, const float* __restrict__ b3,
    const float* __restrict__ b4, const float* __restrict__ b5,
    float* __restrict__ G2, float* __restrict__ G3,
    float* __restrict__ G4it, float* __restrict__ prey)
{
    __shared__ float lp[4][64], its[4][64], ln[4][64], ee[4][128];
    const int g = threadIdx.x >> 6;
    const int d = threadIdx.x & 63;
    const int row = blockIdx.x * 4 + g;
    const int t = row % L;
    lp[g][d]  = (t == 0) ? 0.0f : allL[(row - 1) * 64 + d];
    its[g][d] = it_embed[(size_t)it_data[row] * 64 + d];
    ln[g][d]  = allL[row * 64 + d];
    const int e = e_data[row];
    ee[g][d]      = e_embed[(size_t)e * DE + d];
    ee[g][64 + d] = e_embed[(size_t)e * DE + 64 + d];
    __syncthreads();
    float g2 = b2[d], g3 = b3[d], g4 = b4[d], py = b5[d];
    #pragma unroll 4
    for (int k = 0; k < 64; ++k) {
        const float l0 = lp[g][k], i0 = its[g][k], n0 = ln[g][k];
        g2 += W2T[k * 64 + d] * l0 + W2T[(64 + k) * 64 + d] * i0 + W2T[(128 + k) * 64 + d] * n0;
        g3 += W3T[k * 64 + d] * l0 + W3T[(64 + k) * 64 + d] * i0 + W3T[(128 + k) * 64 + d] * n0;
        g4 += W4T[(128 + k) * 64 + d] * i0;
        py += W5T[k * 64 + d] * ee[g][k] + W5T[(64 + k) * 64 + d] * ee[g][64 + k];
    }
    G2[row * 64 + d]   = g2;
    G3[row * 64 + d]   = g3;
    G4it[row * 64 + d] = g4;
    prey[row * 64 + d] = py;
}

// ---------------- persistent recurrence: all 99 steps -----------------------
// grid (B, 8): b = blockIdx.x, cx = blockIdx.y (s-chunk of 64 rows). 256 thr.
// PLAIN launch; ~89KB LDS -> 1 block/CU, 256 blocks co-resident.
// Cross-block h_tilde exchange: relaxed AGENT-scope (sc1, LLC-coherent)
// stores/loads, NO fences. Publish drain is wave-0-local (s_waitcnt) so
// waves 1-3 run ahead into the next GEMM. Counters padded to 128B each.
__global__ __launch_bounds__(256, 1) void k_steps(
    float* __restrict__ htb, unsigned* __restrict__ cnt,
    const float* __restrict__ G2, const float* __restrict__ G3,
    const float* __restrict__ G4it,
    const float* __restrict__ W2T, const float* __restrict__ W3T,
    const float* __restrict__ W4T,
    const float* __restrict__ q_matrix, const int* __restrict__ e_data,
    const float* __restrict__ h0)
{
    __shared__ float hS[64][68];      // h rows, padded
    __shared__ float waS[64][64];     // W4a, k-major
    __shared__ float wbS[64][64];     // W4b, k-major
    __shared__ float w2S[64][64];     // W2 h_tilde-part, k-major
    __shared__ float w3S[64][64];     // W3 h_tilde-part, k-major
    __shared__ float HTP[64], LGs[64], Vs[64];
    __shared__ float qAB[2][64];      // ping-pong: q[e_t], q[e_{t+1}] rows
    __shared__ float sred[4][64], s2red[4][64], s3red[4][64], wred[4][64];
    __shared__ int eRow[104];

    const int tid = threadIdx.x;
    const int b  = blockIdx.x;
    const int cx = blockIdx.y;
    const int d  = tid & 63;
    const int kg = tid >> 6;
    const int r0 = cx * 64;
    const int rt = tid >> 4;
    const int dt = tid & 15;
    unsigned* cntb = &cnt[b * 32];

    // one-time staging
    for (int i = tid; i < 4096; i += 256) {
        const int k = i >> 6, dd = i & 63;
        waS[k][dd] = W4T[i];
        wbS[k][dd] = W4T[64 * 64 + i];
        w2S[k][dd] = W2T[192 * 64 + i];
        w3S[k][dd] = W3T[192 * 64 + i];
    }
    for (int i = tid; i < 4096; i += 256) {
        const int r = i >> 6, dd = i & 63, gr = r0 + r;
        hS[r][dd] = (gr < S) ? h0[gr * 64 + dd] : 0.0f;
    }
    if (tid < L) eRow[tid] = e_data[b * L + tid];
    __syncthreads();

    // initial q[e_0] row chunk + h_tilde_0 partial
    if (tid < 64) {
        const int gr = r0 + tid;
        qAB[0][tid] = (gr < S) ? q_matrix[(size_t)eRow[0] * S + gr] : 0.0f;
    }
    __syncthreads();
    if (tid < 64) {
        float s = 0.0f;
        #pragma unroll 8
        for (int r = 0; r < 64; ++r) s += qAB[0][r] * hS[r][tid];
        __hip_atomic_store(&htb[((size_t)0 * B + b) * 512 + (size_t)cx * 64 + tid], s,
                           __ATOMIC_RELAXED, __HIP_MEMORY_SCOPE_AGENT);
    }
    if (tid < 64) { asm volatile("s_waitcnt vmcnt(0)" ::: "memory"); }
    if (tid == 0)
        __hip_atomic_fetch_add(cntb, 1u, __ATOMIC_RELAXED, __HIP_MEMORY_SCOPE_AGENT);

    for (int t = 0; t < L - 1; ++t) {
        // 0) early loads (wave 0 only): q[e_{t+1}] chunk + gate constants.
        //    Addresses come from LDS-cached eRow -> no dependent global stall.
        float qn = 0.0f, g2v = 0.0f, g3v = 0.0f, g4v = 0.0f;
        if (tid < 64) {
            const int en = eRow[t + 1];
            const int gr = r0 + tid;
            if (gr < S) qn = q_matrix[(size_t)en * S + gr];
            g2v = G2[(b * L + t) * 64 + d];
            g3v = G3[(b * L + t) * 64 + d];
            g4v = G4it[(b * L + t) * 64 + d];
        }

        // 1) big GEMM: acc = h_chunk(64x64) @ W4a^T — independent of h_tilde.
        float acc[4][4];
        #pragma unroll
        for (int j = 0; j < 4; ++j) { acc[j][0] = 0.f; acc[j][1] = 0.f; acc[j][2] = 0.f; acc[j][3] = 0.f; }
        #pragma unroll
        for (int k4 = 0; k4 < 16; ++k4) {
            float4 hv[4], wv[4];
            #pragma unroll
            for (int j = 0; j < 4; ++j) hv[j] = *(const float4*)&hS[rt * 4 + j][k4 * 4];
            #pragma unroll
            for (int j = 0; j < 4; ++j) wv[j] = *(const float4*)&waS[k4 * 4 + j][dt * 4];
            #pragma unroll
            for (int j = 0; j < 4; ++j) {
                const float a0 = hv[j].x, a1 = hv[j].y, a2 = hv[j].z, a3 = hv[j].w;
                acc[j][0] += a0 * wv[0].x + a1 * wv[1].x + a2 * wv[2].x + a3 * wv[3].x;
                acc[j][1] += a0 * wv[0].y + a1 * wv[1].y + a2 * wv[2].y + a3 * wv[3].y;
                acc[j][2] += a0 * wv[0].z + a1 * wv[1].z + a2 * wv[2].z + a3 * wv[3].z;
                acc[j][3] += a0 * wv[0].w + a1 * wv[1].w + a2 * wv[2].w + a3 * wv[3].w;
            }
        }

        // 2) wait for all 8 partials of h_tilde_t (no-sleep first check)
        if (tid == 0) {
            const unsigned want = 8u * (unsigned)(t + 1);
            unsigned v = __hip_atomic_load(cntb, __ATOMIC_RELAXED, __HIP_MEMORY_SCOPE_AGENT);
            unsigned guard = 0;
            while (v < want && ++guard < (1u << 22)) {
                __builtin_amdgcn_s_sleep(1);
                v = __hip_atomic_load(cntb, __ATOMIC_RELAXED, __HIP_MEMORY_SCOPE_AGENT);
            }
        }
        __syncthreads();
        asm volatile("" ::: "memory");

        // 3) load partials (LLC-coherent), stash q[e_{t+1}]
        const float* hp_base = &htb[((size_t)t * B + b) * 512];
        const float p0 = __hip_atomic_load(hp_base + (2 * kg) * 64 + d,
                                           __ATOMIC_RELAXED, __HIP_MEMORY_SCOPE_AGENT);
        const float p1 = __hip_atomic_load(hp_base + (2 * kg + 1) * 64 + d,
                                           __ATOMIC_RELAXED, __HIP_MEMORY_SCOPE_AGENT);
        sred[kg][d] = p0 + p1;
        if (tid < 64) qAB[(t + 1) & 1][d] = qn;
        __syncthreads();
        if (tid < 64) HTP[d] = sred[0][d] + sred[1][d] + sred[2][d] + sred[3][d];
        __syncthreads();
        {
            float a2 = 0.f, a3 = 0.f;
            #pragma unroll
            for (int kk = 0; kk < 16; ++kk) {
                const int k = kg * 16 + kk;
                const float hp = HTP[k];
                a2 += w2S[k][d] * hp;
                a3 += w3S[k][d] * hp;
            }
            s2red[kg][d] = a2; s3red[kg][d] = a3;
        }
        __syncthreads();
        if (tid < 64) {
            const float g2 = g2v + s2red[0][d] + s2red[1][d] + s2red[2][d] + s2red[3][d];
            const float g3 = g3v + s3red[0][d] + s3red[1][d] + s3red[2][d] + s3red[3][d];
            LGs[d] = sigm(g3) * (tanhf(g2) + 1.0f) * 0.5f;
        }
        __syncthreads();
        if (tid < 64) {                       // V = g4 + W4b @ LG, single wave
            float v = g4v;
            #pragma unroll 8
            for (int k = 0; k < 64; ++k) v += wbS[k][d] * LGs[k];
            Vs[d] = v;
        }
        __syncthreads();

        // 4) epilogue: h = qe*LG + sigmoid(acc + V)*h_old; partial qn.h_new
        const float* qeS = qAB[t & 1];
        const float* qnS = qAB[(t + 1) & 1];
        float part[4] = {0.f, 0.f, 0.f, 0.f};
        const float lg0 = LGs[dt * 4], lg1 = LGs[dt * 4 + 1], lg2 = LGs[dt * 4 + 2], lg3 = LGs[dt * 4 + 3];
        const float v0 = Vs[dt * 4], v1 = Vs[dt * 4 + 1], v2 = Vs[dt * 4 + 2], v3 = Vs[dt * 4 + 3];
        #pragma unroll
        for (int j = 0; j < 4; ++j) {
            const int r = rt * 4 + j;
            const float qer = qeS[r], qnr = qnS[r];
            const float4 hold = *(const float4*)&hS[r][dt * 4];
            const float hn0 = qer * lg0 + sigm(acc[j][0] + v0) * hold.x;
            const float hn1 = qer * lg1 + sigm(acc[j][1] + v1) * hold.y;
            const float hn2 = qer * lg2 + sigm(acc[j][2] + v2) * hold.z;
            const float hn3 = qer * lg3 + sigm(acc[j][3] + v3) * hold.w;
            hS[r][dt * 4]     = hn0;
            hS[r][dt * 4 + 1] = hn1;
            hS[r][dt * 4 + 2] = hn2;
            hS[r][dt * 4 + 3] = hn3;
            part[0] += qnr * hn0; part[1] += qnr * hn1;
            part[2] += qnr * hn2; part[3] += qnr * hn3;
        }
        #pragma unroll
        for (int i = 0; i < 4; ++i) {
            float v = part[i];
            v += __shfl_xor(v, 16);
            v += __shfl_xor(v, 32);
            part[i] = v;
        }
        const int wid = tid >> 6, lane = tid & 63;
        if (lane < 16) {
            #pragma unroll
            for (int i = 0; i < 4; ++i) wred[wid][lane * 4 + i] = part[i];
        }
        __syncthreads();

        // 5) publish h_tilde_{t+1} partial: wave-0-local drain, NO block
        //    barrier — waves 1..3 run ahead into the next step's GEMM.
        if (tid < 64) {
            const float s = wred[0][d] + wred[1][d] + wred[2][d] + wred[3][d];
            __hip_atomic_store(&htb[((size_t)(t + 1) * B + b) * 512 + (size_t)cx * 64 + d], s,
                               __ATOMIC_RELAXED, __HIP_MEMORY_SCOPE_AGENT);
        }
        if (tid < 64) { asm volatile("s_waitcnt vmcnt(0)" ::: "memory"); }
        if (tid == 0)
            __hip_atomic_fetch_add(cntb, 1u, __ATOMIC_RELAXED, __HIP_MEMORY_SCOPE_AGENT);
    }
}

// ---------------- epilogue: y_t for t=1..99 --------------------------------
__global__ __launch_bounds__(64) void k_y(
    const float* __restrict__ htb, const float* __restrict__ prey,
    const float* __restrict__ W5T, float* __restrict__ pred)
{
    __shared__ float HT[64];
    const int j = blockIdx.x + 1;    // 1..99
    const int b = blockIdx.y;
    const int d = threadIdx.x;
    float s = 0.0f;
    #pragma unroll
    for (int c = 0; c < 8; ++c)
        s += htb[((size_t)j * B + b) * 512 + c * 64 + d];
    HT[d] = s;
    __syncthreads();
    float acc = prey[(b * L + j) * 64 + d];
    #pragma unroll 8
    for (int k = 0; k < 64; ++k) acc += W5T[(128 + k) * 64 + d] * HT[k];
    float y = sigm(acc);
    #pragma unroll
    for (int m = 1; m < 64; m <<= 1) y += __shfl_xor(y, m);
    if (d == 0) pred[b * L + j] = y * (1.0f / 64.0f);
}

} // namespace

extern "C" void kernel_launch(void* const* d_in, const int* in_sizes, int n_in,
                              void* d_out, int out_size, void* d_ws, size_t ws_size,
                              hipStream_t stream)
{
    const int*   e_data   = (const int*)d_in[0];
    const int*   a_data   = (const int*)d_in[1];
    const int*   at_data  = (const int*)d_in[2];
    const int*   it_data  = (const int*)d_in[3];
    const float* q_matrix = (const float*)d_in[4];
    const float* h0       = (const float*)d_in[5];
    const float* e_embed  = (const float*)d_in[6];
    const float* at_embed = (const float*)d_in[7];
    const float* it_embed = (const float*)d_in[8];
    const float* W1 = (const float*)d_in[9];  const float* b1 = (const float*)d_in[10];
    const float* W2 = (const float*)d_in[11]; const float* b2 = (const float*)d_in[12];
    const float* W3 = (const float*)d_in[13]; const float* b3 = (const float*)d_in[14];
    const float* W4 = (const float*)d_in[15]; const float* b4 = (const float*)d_in[16];
    const float* W5 = (const float*)d_in[17]; const float* b5 = (const float*)d_in[18];
    float* pred = (float*)d_out;

    float* ws = (float*)d_ws;
    float* W1T  = ws;                         // 256*64 = 16384
    float* W2T  = W1T  + 16384;
    float* W3T  = W2T  + 16384;
    float* W4T  = W3T  + 16384;               // 192*64 = 12288
    float* W5T  = W4T  + 12288;
    float* allL = W5T  + 12288;               // B*L*64 = 204800
    float* G2   = allL + 204800;
    float* G3   = G2   + 204800;
    float* G4it = G3   + 204800;
    float* prey = G4it + 204800;
    float* htb  = prey + 204800;              // L*B*512 = 1638400
    unsigned* cnt = (unsigned*)(htb + 1638400);   // 1024 padded counters
    // total ~10.9 MB

    hipLaunchKernelGGL(k_init, dim3(64), dim3(256), 0, stream,
                       W1, W2, W3, W4, W5, W1T, W2T, W3T, W4T, W5T, cnt, pred);
    hipLaunchKernelGGL(k_all_learning, dim3(B * L / 4), dim3(256), 0, stream,
                       e_data, a_data, at_data, e_embed, at_embed, W1T, b1, allL);
    hipLaunchKernelGGL(k_pre, dim3(B * L / 4), dim3(256), 0, stream,
                       e_data, it_data, e_embed, it_embed, allL,
                       W2T, W3T, W4T, W5T, b2, b3, b4, b5, G2, G3, G4it, prey);
    hipLaunchKernelGGL(k_steps, dim3(B, 8), dim3(256), 0, stream,
                       htb, cnt, G2, G3, G4it, W2T, W3T, W4T,
                       q_matrix, e_data, h0);
    hipLaunchKernelGGL(k_y, dim3(L - 1, B), dim3(64), 0, stream,
                       htb, prey, W5T, pred);
}

// Round 8
// 1046.698 us; speedup vs baseline: 2.8965x; 1.0059x over previous
//
#include <hip/hip_runtime.h>
#include <hip/hip_bf16.h>

namespace {

constexpr int B  = 32;
constexpr int L  = 100;
constexpr int S  = 501;
constexpr int DK = 64;
constexpr int DE = 128;

typedef unsigned long long u64;

__device__ __forceinline__ float sigm(float x) {
    return __fdividef(1.0f, 1.0f + __expf(-x));
}

// ---------------- init: transpose weights, zero htb2 tags, pred[:,0] -------
__global__ __launch_bounds__(256) void k_init(
    const float* __restrict__ W1, const float* __restrict__ W2,
    const float* __restrict__ W3, const float* __restrict__ W4,
    const float* __restrict__ W5,
    float* __restrict__ W1T, float* __restrict__ W2T, float* __restrict__ W3T,
    float* __restrict__ W4T, float* __restrict__ W5T,
    u64* __restrict__ htb2, float* __restrict__ pred)
{
    const int idx = blockIdx.x * 256 + threadIdx.x;
    const int st  = gridDim.x * 256;
    for (int i = idx; i < 64 * 256; i += st) {
        int dd = i >> 8, kk = i & 255;
        W1T[kk * 64 + dd] = W1[i];
        W2T[kk * 64 + dd] = W2[i];
        W3T[kk * 64 + dd] = W3[i];
    }
    for (int i = idx; i < 64 * 192; i += st) {
        int dd = i / 192, kk = i % 192;
        W4T[kk * 64 + dd] = W4[i];
        W5T[kk * 64 + dd] = W5[i];
    }
    // zero the TAG half (low 32 bits, little-endian) of every htb2 word with
    // cache-bypassing (sc1) stores so k_steps' sc1 polls can never see a
    // stale tag from a previous graph replay.
    const int NW = L * B * 8 * 64;
    for (int i = idx; i < NW; i += st) {
        unsigned* tag = (unsigned*)&htb2[i];
        __hip_atomic_store(tag, 0u, __ATOMIC_RELAXED, __HIP_MEMORY_SCOPE_AGENT);
    }
    if (idx < B) pred[idx * L] = 0.0f;
}

// ---------------- all_learning = concat(e,at,a) @ W1^T + b1 ----------------
__global__ __launch_bounds__(256) void k_all_learning(
    const int* __restrict__ e_data, const int* __restrict__ a_data,
    const int* __restrict__ at_data,
    const float* __restrict__ e_embed, const float* __restrict__ at_embed,
    const float* __restrict__ W1T, const float* __restrict__ b1,
    float* __restrict__ allL)
{
    __shared__ float in_s[4][257];
    const int g = threadIdx.x >> 6;
    const int d = threadIdx.x & 63;
    const int row = blockIdx.x * 4 + g;
    const int e  = e_data[row];
    const int at = at_data[row];
    in_s[g][d]       = e_embed[(size_t)e * DE + d];
    in_s[g][64 + d]  = e_embed[(size_t)e * DE + 64 + d];
    in_s[g][128 + d] = at_embed[(size_t)at * DK + d];
    in_s[g][192 + d] = (float)a_data[row];
    __syncthreads();
    float acc = b1[d];
    #pragma unroll 8
    for (int k = 0; k < 256; ++k) acc += W1T[k * 64 + d] * in_s[g][k];
    allL[row * DK + d] = acc;
}

// ---------------- G2,G3 (non-recurrent parts), G4it, prey ------------------
__global__ __launch_bounds__(256) void k_pre(
    const int* __restrict__ e_data, const int* __restrict__ it_data,
    const float* __restrict__ e_embed, const float* __restrict__ it_embed,
    const float* __restrict__ allL,
    const float* __restrict__ W2T, const float* __restrict__ W3T,
    const float* __restrict__ W4T, const float* __restrict__ W5T,
    const float* __restrict__ b2, const float* __restrict__ b3,
    const float* __restrict__ b4, const float* __restrict__ b5,
    float* __restrict__ G2, float* __restrict__ G3,
    float* __restrict__ G4it, float* __restrict__ prey)
{
    __shared__ float lp[4][64], its[4][64], ln[4][64], ee[4][128];
    const int g = threadIdx.x >> 6;
    const int d = threadIdx.x & 63;
    const int row = blockIdx.x * 4 + g;
    const int t = row % L;
    lp[g][d]  = (t == 0) ? 0.0f : allL[(row - 1) * 64 + d];
    its[g][d] = it_embed[(size_t)it_data[row] * 64 + d];
    ln[g][d]  = allL[row * 64 + d];
    const int e = e_data[row];
    ee[g][d]      = e_embed[(size_t)e * DE + d];
    ee[g][64 + d] = e_embed[(size_t)e * DE + 64 + d];
    __syncthreads();
    float g2 = b2[d], g3 = b3[d], g4 = b4[d], py = b5[d];
    #pragma unroll 4
    for (int k = 0; k < 64; ++k) {
        const float l0 = lp[g][k], i0 = its[g][k], n0 = ln[g][k];
        g2 += W2T[k * 64 + d] * l0 + W2T[(64 + k) * 64 + d] * i0 + W2T[(128 + k) * 64 + d] * n0;
        g3 += W3T[k * 64 + d] * l0 + W3T[(64 + k) * 64 + d] * i0 + W3T[(128 + k) * 64 + d] * n0;
        g4 += W4T[(128 + k) * 64 + d] * i0;
        py += W5T[k * 64 + d] * ee[g][k] + W5T[(64 + k) * 64 + d] * ee[g][64 + k];
    }
    G2[row * 64 + d]   = g2;
    G3[row * 64 + d]   = g3;
    G4it[row * 64 + d] = g4;
    prey[row * 64 + d] = py;
}

// ---------------- persistent recurrence: all 99 steps -----------------------
// grid (B, 8): b = blockIdx.x, cx = blockIdx.y (s-chunk of 64 rows). 256 thr.
// ~89KB LDS -> 1 block/CU, 256 blocks co-resident (plain launch).
// DATA-AS-FLAG sync: each h_tilde partial element is a tagged u64
// (float_bits<<32 | step_tag) written with ONE relaxed agent-scope (sc1)
// atomic store. Consumers poll the words directly until tag matches; tag and
// payload travel atomically, so no fence, drain, or counter is needed.
// Poll loads are issued MID-GEMM so the LLC latency hides under compute.
__global__ __launch_bounds__(256, 1) void k_steps(
    u64* __restrict__ htb2,
    const float* __restrict__ G2, const float* __restrict__ G3,
    const float* __restrict__ G4it,
    const float* __restrict__ W2T, const float* __restrict__ W3T,
    const float* __restrict__ W4T,
    const float* __restrict__ q_matrix, const int* __restrict__ e_data,
    const float* __restrict__ h0)
{
    __shared__ float hS[64][68];      // h rows, padded
    __shared__ float waS[64][64];     // W4a, k-major
    __shared__ float wbS[64][64];     // W4b, k-major
    __shared__ float w2S[64][64];     // W2 h_tilde-part, k-major
    __shared__ float w3S[64][64];     // W3 h_tilde-part, k-major
    __shared__ float LGs[64], Vs[64];
    __shared__ float qAB[2][64];      // ping-pong: q[e_t], q[e_{t+1}] rows
    __shared__ float sred[4][64], s2red[4][64], s3red[4][64], wred[4][64];
    __shared__ int eRow[104];

    const int tid = threadIdx.x;
    const int b  = blockIdx.x;
    const int cx = blockIdx.y;
    const int d  = tid & 63;
    const int kg = tid >> 6;
    const int r0 = cx * 64;
    const int rt = tid >> 4;
    const int dt = tid & 15;

    // one-time staging
    for (int i = tid; i < 4096; i += 256) {
        const int k = i >> 6, dd = i & 63;
        waS[k][dd] = W4T[i];
        wbS[k][dd] = W4T[64 * 64 + i];
        w2S[k][dd] = W2T[192 * 64 + i];
        w3S[k][dd] = W3T[192 * 64 + i];
    }
    for (int i = tid; i < 4096; i += 256) {
        const int r = i >> 6, dd = i & 63, gr = r0 + r;
        hS[r][dd] = (gr < S) ? h0[gr * 64 + dd] : 0.0f;
    }
    if (tid < L) eRow[tid] = e_data[b * L + tid];
    __syncthreads();

    // initial q[e_0] row chunk + tagged publish of h_tilde_0 partial (tag 1)
    if (tid < 64) {
        const int gr = r0 + tid;
        qAB[0][tid] = (gr < S) ? q_matrix[(size_t)eRow[0] * S + gr] : 0.0f;
    }
    __syncthreads();
    if (tid < 64) {
        float s = 0.0f;
        #pragma unroll 8
        for (int r = 0; r < 64; ++r) s += qAB[0][r] * hS[r][tid];
        const u64 pv = ((u64)__float_as_uint(s) << 32) | 1u;
        __hip_atomic_store(&htb2[((size_t)0 * B + b) * 512 + (size_t)cx * 64 + tid], pv,
                           __ATOMIC_RELAXED, __HIP_MEMORY_SCOPE_AGENT);
    }

    for (int t = 0; t < L - 1; ++t) {
        // 0) early loads (wave 0 only): q[e_{t+1}] chunk + gate constants
        float qn = 0.0f, g2v = 0.0f, g3v = 0.0f, g4v = 0.0f;
        if (tid < 64) {
            const int en = eRow[t + 1];
            const int gr = r0 + tid;
            if (gr < S) qn = q_matrix[(size_t)en * S + gr];
            g2v = G2[(b * L + t) * 64 + d];
            g3v = G3[(b * L + t) * 64 + d];
            g4v = G4it[(b * L + t) * 64 + d];
        }

        const u64* slot = &htb2[((size_t)t * B + b) * 512];
        const u64* a0 = slot + (size_t)(2 * kg) * 64 + d;
        const u64* a1 = slot + (size_t)(2 * kg + 1) * 64 + d;
        const unsigned want = (unsigned)(t + 1);

        // 1) big GEMM: acc = h_chunk(64x64) @ W4a^T — first half
        float acc[4][4];
        #pragma unroll
        for (int j = 0; j < 4; ++j) { acc[j][0] = 0.f; acc[j][1] = 0.f; acc[j][2] = 0.f; acc[j][3] = 0.f; }
        #pragma unroll
        for (int k4 = 0; k4 < 8; ++k4) {
            float4 hv[4], wv[4];
            #pragma unroll
            for (int j = 0; j < 4; ++j) hv[j] = *(const float4*)&hS[rt * 4 + j][k4 * 4];
            #pragma unroll
            for (int j = 0; j < 4; ++j) wv[j] = *(const float4*)&waS[k4 * 4 + j][dt * 4];
            #pragma unroll
            for (int j = 0; j < 4; ++j) {
                const float x0 = hv[j].x, x1 = hv[j].y, x2 = hv[j].z, x3 = hv[j].w;
                acc[j][0] += x0 * wv[0].x + x1 * wv[1].x + x2 * wv[2].x + x3 * wv[3].x;
                acc[j][1] += x0 * wv[0].y + x1 * wv[1].y + x2 * wv[2].y + x3 * wv[3].y;
                acc[j][2] += x0 * wv[0].z + x1 * wv[1].z + x2 * wv[2].z + x3 * wv[3].z;
                acc[j][3] += x0 * wv[0].w + x1 * wv[1].w + x2 * wv[2].w + x3 * wv[3].w;
            }
        }

        // speculative tagged loads — latency hides under GEMM second half
        u64 v0 = __hip_atomic_load(a0, __ATOMIC_RELAXED, __HIP_MEMORY_SCOPE_AGENT);
        u64 v1 = __hip_atomic_load(a1, __ATOMIC_RELAXED, __HIP_MEMORY_SCOPE_AGENT);

        // GEMM second half
        #pragma unroll
        for (int k4 = 8; k4 < 16; ++k4) {
            float4 hv[4], wv[4];
            #pragma unroll
            for (int j = 0; j < 4; ++j) hv[j] = *(const float4*)&hS[rt * 4 + j][k4 * 4];
            #pragma unroll
            for (int j = 0; j < 4; ++j) wv[j] = *(const float4*)&waS[k4 * 4 + j][dt * 4];
            #pragma unroll
            for (int j = 0; j < 4; ++j) {
                const float x0 = hv[j].x, x1 = hv[j].y, x2 = hv[j].z, x3 = hv[j].w;
                acc[j][0] += x0 * wv[0].x + x1 * wv[1].x + x2 * wv[2].x + x3 * wv[3].x;
                acc[j][1] += x0 * wv[0].y + x1 * wv[1].y + x2 * wv[2].y + x3 * wv[3].y;
                acc[j][2] += x0 * wv[0].z + x1 * wv[1].z + x2 * wv[2].z + x3 * wv[3].z;
                acc[j][3] += x0 * wv[0].w + x1 * wv[1].w + x2 * wv[2].w + x3 * wv[3].w;
            }
        }

        // 2) retry until both tags match (usually 0 retries in steady state)
        {
            unsigned g = 0;
            while ((unsigned)v0 != want && ++g < (1u << 24))
                v0 = __hip_atomic_load(a0, __ATOMIC_RELAXED, __HIP_MEMORY_SCOPE_AGENT);
            g = 0;
            while ((unsigned)v1 != want && ++g < (1u << 24))
                v1 = __hip_atomic_load(a1, __ATOMIC_RELAXED, __HIP_MEMORY_SCOPE_AGENT);
        }
        const float p0 = __uint_as_float((unsigned)(v0 >> 32));
        const float p1 = __uint_as_float((unsigned)(v1 >> 32));

        // 3) gates. sred[kg][d] = partial pair sum; HTP fused into w2/w3 dots
        sred[kg][d] = p0 + p1;
        if (tid < 64) qAB[(t + 1) & 1][d] = qn;
        __syncthreads();
        {
            float a2 = 0.f, a3 = 0.f;
            #pragma unroll
            for (int kk = 0; kk < 16; ++kk) {
                const int k = kg * 16 + kk;
                const float hp = sred[0][k] + sred[1][k] + sred[2][k] + sred[3][k];
                a2 += w2S[k][d] * hp;
                a3 += w3S[k][d] * hp;
            }
            s2red[kg][d] = a2; s3red[kg][d] = a3;
        }
        __syncthreads();
        if (tid < 64) {
            const float g2 = g2v + s2red[0][d] + s2red[1][d] + s2red[2][d] + s2red[3][d];
            const float g3 = g3v + s3red[0][d] + s3red[1][d] + s3red[2][d] + s3red[3][d];
            LGs[d] = sigm(g3) * (tanhf(g2) + 1.0f) * 0.5f;
        }
        __syncthreads();
        if (tid < 64) {                       // V = g4 + W4b @ LG, single wave
            float v = g4v;
            #pragma unroll 8
            for (int k = 0; k < 64; ++k) v += wbS[k][d] * LGs[k];
            Vs[d] = v;
        }
        __syncthreads();

        // 4) epilogue: h = qe*LG + sigmoid(acc + V)*h_old; partial qn.h_new
        const float* qeS = qAB[t & 1];
        const float* qnS = qAB[(t + 1) & 1];
        float part[4] = {0.f, 0.f, 0.f, 0.f};
        const float lg0 = LGs[dt * 4], lg1 = LGs[dt * 4 + 1], lg2 = LGs[dt * 4 + 2], lg3 = LGs[dt * 4 + 3];
        const float v0f = Vs[dt * 4], v1f = Vs[dt * 4 + 1], v2f = Vs[dt * 4 + 2], v3f = Vs[dt * 4 + 3];
        #pragma unroll
        for (int j = 0; j < 4; ++j) {
            const int r = rt * 4 + j;
            const float qer = qeS[r], qnr = qnS[r];
            const float4 hold = *(const float4*)&hS[r][dt * 4];
            const float hn0 = qer * lg0 + sigm(acc[j][0] + v0f) * hold.x;
            const float hn1 = qer * lg1 + sigm(acc[j][1] + v1f) * hold.y;
            const float hn2 = qer * lg2 + sigm(acc[j][2] + v2f) * hold.z;
            const float hn3 = qer * lg3 + sigm(acc[j][3] + v3f) * hold.w;
            hS[r][dt * 4]     = hn0;
            hS[r][dt * 4 + 1] = hn1;
            hS[r][dt * 4 + 2] = hn2;
            hS[r][dt * 4 + 3] = hn3;
            part[0] += qnr * hn0; part[1] += qnr * hn1;
            part[2] += qnr * hn2; part[3] += qnr * hn3;
        }
        #pragma unroll
        for (int i = 0; i < 4; ++i) {
            float v = part[i];
            v += __shfl_xor(v, 16);
            v += __shfl_xor(v, 32);
            part[i] = v;
        }
        const int wid = tid >> 6, lane = tid & 63;
        if (lane < 16) {
            #pragma unroll
            for (int i = 0; i < 4; ++i) wred[wid][lane * 4 + i] = part[i];
        }
        __syncthreads();

        // 5) tagged publish of h_tilde_{t+1} partial (tag t+2), fire & forget
        if (tid < 64) {
            const float s = wred[0][d] + wred[1][d] + wred[2][d] + wred[3][d];
            const u64 pv = ((u64)__float_as_uint(s) << 32) | (unsigned)(t + 2);
            __hip_atomic_store(&htb2[((size_t)(t + 1) * B + b) * 512 + (size_t)cx * 64 + d], pv,
                               __ATOMIC_RELAXED, __HIP_MEMORY_SCOPE_AGENT);
        }
    }
}

// ---------------- epilogue: y_t for t=1..99 --------------------------------
__global__ __launch_bounds__(64) void k_y(
    const u64* __restrict__ htb2, const float* __restrict__ prey,
    const float* __restrict__ W5T, float* __restrict__ pred)
{
    __shared__ float HT[64];
    const int j = blockIdx.x + 1;    // 1..99
    const int b = blockIdx.y;
    const int d = threadIdx.x;
    float s = 0.0f;
    #pragma unroll
    for (int c = 0; c < 8; ++c) {
        const u64 v = htb2[((size_t)j * B + b) * 512 + (size_t)c * 64 + d];
        s += __uint_as_float((unsigned)(v >> 32));
    }
    HT[d] = s;
    __syncthreads();
    float acc = prey[(b * L + j) * 64 + d];
    #pragma unroll 8
    for (int k = 0; k < 64; ++k) acc += W5T[(128 + k) * 64 + d] * HT[k];
    float y = sigm(acc);
    #pragma unroll
    for (int m = 1; m < 64; m <<= 1) y += __shfl_xor(y, m);
    if (d == 0) pred[b * L + j] = y * (1.0f / 64.0f);
}

} // namespace

extern "C" void kernel_launch(void* const* d_in, const int* in_sizes, int n_in,
                              void* d_out, int out_size, void* d_ws, size_t ws_size,
                              hipStream_t stream)
{
    const int*   e_data   = (const int*)d_in[0];
    const int*   a_data   = (const int*)d_in[1];
    const int*   at_data  = (const int*)d_in[2];
    const int*   it_data  = (const int*)d_in[3];
    const float* q_matrix = (const float*)d_in[4];
    const float* h0       = (const float*)d_in[5];
    const float* e_embed  = (const float*)d_in[6];
    const float* at_embed = (const float*)d_in[7];
    const float* it_embed = (const float*)d_in[8];
    const float* W1 = (const float*)d_in[9];  const float* b1 = (const float*)d_in[10];
    const float* W2 = (const float*)d_in[11]; const float* b2 = (const float*)d_in[12];
    const float* W3 = (const float*)d_in[13]; const float* b3 = (const float*)d_in[14];
    const float* W4 = (const float*)d_in[15]; const float* b4 = (const float*)d_in[16];
    const float* W5 = (const float*)d_in[17]; const float* b5 = (const float*)d_in[18];
    float* pred = (float*)d_out;

    // layout: htb2 (u64, 8B-aligned) first, then fp32 arrays
    u64* htb2 = (u64*)d_ws;                       // L*B*512 u64 = 13.1 MB
    float* fws  = (float*)(htb2 + (size_t)L * B * 512);
    float* W1T  = fws;                            // 256*64
    float* W2T  = W1T  + 16384;
    float* W3T  = W2T  + 16384;
    float* W4T  = W3T  + 16384;                   // 192*64
    float* W5T  = W4T  + 12288;
    float* allL = W5T  + 12288;                   // B*L*64
    float* G2   = allL + 204800;
    float* G3   = G2   + 204800;
    float* G4it = G3   + 204800;
    float* prey = G4it + 204800;
    // total ~17.5 MB

    hipLaunchKernelGGL(k_init, dim3(1024), dim3(256), 0, stream,
                       W1, W2, W3, W4, W5, W1T, W2T, W3T, W4T, W5T, htb2, pred);
    hipLaunchKernelGGL(k_all_learning, dim3(B * L / 4), dim3(256), 0, stream,
                       e_data, a_data, at_data, e_embed, at_embed, W1T, b1, allL);
    hipLaunchKernelGGL(k_pre, dim3(B * L / 4), dim3(256), 0, stream,
                       e_data, it_data, e_embed, it_embed, allL,
                       W2T, W3T, W4T, W5T, b2, b3, b4, b5, G2, G3, G4it, prey);
    hipLaunchKernelGGL(k_steps, dim3(B, 8), dim3(256), 0, stream,
                       htb2, G2, G3, G4it, W2T, W3T, W4T,
                       q_matrix, e_data, h0);
    hipLaunchKernelGGL(k_y, dim3(L - 1, B), dim3(64), 0, stream,
                       htb2, prey, W5T, pred);
}

// Round 9
// 798.776 us; speedup vs baseline: 3.7955x; 1.3104x over previous
//
#include <hip/hip_runtime.h>
#include <hip/hip_bf16.h>

namespace {

constexpr int B  = 32;
constexpr int L  = 100;
constexpr int S  = 501;
constexpr int DK = 64;
constexpr int DE = 128;

typedef __attribute__((ext_vector_type(8))) short short8v;   // 8 bf16 (4 VGPR)
typedef __attribute__((ext_vector_type(4))) float f32x4;
typedef unsigned int u32;

__device__ __forceinline__ float sigm(float x) {
    return __fdividef(1.0f, 1.0f + __expf(-x));
}
// fp32 -> bf16 with round-to-nearest-even
__device__ __forceinline__ unsigned short f2bf(float f) {
    u32 u = __float_as_uint(f);
    u += 0x7FFFu + ((u >> 16) & 1u);
    return (unsigned short)(u >> 16);
}

// ---------------- init: transpose weights (k-major) for pre/y, pred[:,0] ---
__global__ __launch_bounds__(256) void k_init(
    const float* __restrict__ W1, const float* __restrict__ W2,
    const float* __restrict__ W3, const float* __restrict__ W4,
    const float* __restrict__ W5,
    float* __restrict__ W1T, float* __restrict__ W2T, float* __restrict__ W3T,
    float* __restrict__ W4T, float* __restrict__ W5T,
    float* __restrict__ pred)
{
    const int idx = blockIdx.x * 256 + threadIdx.x;
    const int st  = gridDim.x * 256;
    for (int i = idx; i < 64 * 256; i += st) {
        int dd = i >> 8, kk = i & 255;
        W1T[kk * 64 + dd] = W1[i];
        W2T[kk * 64 + dd] = W2[i];
        W3T[kk * 64 + dd] = W3[i];
    }
    for (int i = idx; i < 64 * 192; i += st) {
        int dd = i / 192, kk = i % 192;
        W4T[kk * 64 + dd] = W4[i];
        W5T[kk * 64 + dd] = W5[i];
    }
    if (idx < B) pred[idx * L] = 0.0f;
}

// ---------------- all_learning = concat(e,at,a) @ W1^T + b1 ----------------
__global__ __launch_bounds__(256) void k_all_learning(
    const int* __restrict__ e_data, const int* __restrict__ a_data,
    const int* __restrict__ at_data,
    const float* __restrict__ e_embed, const float* __restrict__ at_embed,
    const float* __restrict__ W1T, const float* __restrict__ b1,
    float* __restrict__ allL)
{
    __shared__ float in_s[4][257];
    const int g = threadIdx.x >> 6;
    const int d = threadIdx.x & 63;
    const int row = blockIdx.x * 4 + g;
    const int e  = e_data[row];
    const int at = at_data[row];
    in_s[g][d]       = e_embed[(size_t)e * DE + d];
    in_s[g][64 + d]  = e_embed[(size_t)e * DE + 64 + d];
    in_s[g][128 + d] = at_embed[(size_t)at * DK + d];
    in_s[g][192 + d] = (float)a_data[row];
    __syncthreads();
    float acc = b1[d];
    #pragma unroll 8
    for (int k = 0; k < 256; ++k) acc += W1T[k * 64 + d] * in_s[g][k];
    allL[row * DK + d] = acc;
}

// ---------------- G2,G3 (non-recurrent parts), G4it, prey ------------------
__global__ __launch_bounds__(256) void k_pre(
    const int* __restrict__ e_data, const int* __restrict__ it_data,
    const float* __restrict__ e_embed, const float* __restrict__ it_embed,
    const float* __restrict__ allL,
    const float* __restrict__ W2T, const float* __restrict__ W3T,
    const float* __restrict__ W4T, const float* __restrict__ W5T,
    const float* __restrict__ b2, const float* __restrict__ b3,
    const float* __restrict__ b4, const float* __restrict__ b5,
    float* __restrict__ G2, float* __restrict__ G3,
    float* __restrict__ G4it, float* __restrict__ prey)
{
    __shared__ float lp[4][64], its[4][64], ln[4][64], ee[4][128];
    const int g = threadIdx.x >> 6;
    const int d = threadIdx.x & 63;
    const int row = blockIdx.x * 4 + g;
    const int t = row % L;
    lp[g][d]  = (t == 0) ? 0.0f : allL[(row - 1) * 64 + d];
    its[g][d] = it_embed[(size_t)it_data[row] * 64 + d];
    ln[g][d]  = allL[row * 64 + d];
    const int e = e_data[row];
    ee[g][d]      = e_embed[(size_t)e * DE + d];
    ee[g][64 + d] = e_embed[(size_t)e * DE + 64 + d];
    __syncthreads();
    float g2 = b2[d], g3 = b3[d], g4 = b4[d], py = b5[d];
    #pragma unroll 4
    for (int k = 0; k < 64; ++k) {
        const float l0 = lp[g][k], i0 = its[g][k], n0 = ln[g][k];
        g2 += W2T[k * 64 + d] * l0 + W2T[(64 + k) * 64 + d] * i0 + W2T[(128 + k) * 64 + d] * n0;
        g3 += W3T[k * 64 + d] * l0 + W3T[(64 + k) * 64 + d] * i0 + W3T[(128 + k) * 64 + d] * n0;
        g4 += W4T[(128 + k) * 64 + d] * i0;
        py += W5T[k * 64 + d] * ee[g][k] + W5T[(64 + k) * 64 + d] * ee[g][64 + k];
    }
    G2[row * 64 + d]   = g2;
    G3[row * 64 + d]   = g3;
    G4it[row * 64 + d] = g4;
    prey[row * 64 + d] = py;
}

// ---------------- persistent recurrence: one block per BATCH ---------------
// grid (B): 32 blocks x 512 threads (8 waves). NO cross-block sync at all.
// h master: fp32 in registers, C-fragment layout (lane owns h[s][d0..d0+3]
// float4s for 16 tiles). bf16 mirror of h in LDS feeds MFMA B-fragments.
// gamma_f computed TRANSPOSED: gf^T[d][s] = sum_k W4a[d][k] * h[s][k] via
// mfma_f32_16x16x32_bf16 (A = W4a frags, held in regs; B = h rows, b128).
// C-frag (col=lane&15 -> s, row=(lane>>4)*4+reg -> d) == the h float4 the
// lane owns, so the epilogue is pure register math.
__global__ __launch_bounds__(512) void k_steps(
    const float* __restrict__ G2, const float* __restrict__ G3,
    const float* __restrict__ G4it,
    const float* __restrict__ W2, const float* __restrict__ W3,
    const float* __restrict__ W4,
    const float* __restrict__ q_matrix, const int* __restrict__ e_data,
    const float* __restrict__ h0, float* __restrict__ hthist)
{
    __shared__ unsigned short hB[512 * 72];   // h mirror, bf16, row-pad 72 (72KB)
    __shared__ float qQ[2][512];              // q[e_t], q[e_{t+1}] ping-pong
    __shared__ float htS[64], LGs[64], Vs[64];
    __shared__ float red[512], red2[512];     // 8-wave reduction scratch
    __shared__ int eRow[128];

    const int tid = threadIdx.x;
    const int b   = blockIdx.x;
    const int l   = tid & 63;     // lane
    const int w   = tid >> 6;     // wave 0..7
    const int lm  = l & 15;       // tile row/col position
    const int lk  = l >> 4;       // k-chunk / reg-quad group 0..3
    const int d   = tid & 63;     // gate-phase d index
    const int kg  = tid >> 6;     // gate-phase k group 0..7

    // ---- per-thread weight registers (gate slices) ----
    float w2r[8], w3r[8], wbr[8];
    #pragma unroll
    for (int j = 0; j < 8; ++j) {
        w2r[j] = W2[d * 256 + 192 + kg * 8 + j];
        w3r[j] = W3[d * 256 + 192 + kg * 8 + j];
        wbr[j] = W4[d * 192 + 64  + kg * 8 + j];
    }

    // ---- A-fragments: W4a[d][k] as bf16, persistent in regs ----
    // A-frag layout (16x16x32): row m = lane&15, k = (lane>>4)*8 + j
    short8v afr[4][2];
    #pragma unroll
    for (int dt = 0; dt < 4; ++dt)
        #pragma unroll
        for (int kc = 0; kc < 2; ++kc) {
            const float* src = W4 + (size_t)(dt * 16 + lm) * 192 + kc * 32 + lk * 8;
            union { unsigned short us[8]; short8v v; } u;
            #pragma unroll
            for (int j = 0; j < 8; ++j) u.us[j] = f2bf(src[j]);
            afr[dt][kc] = u.v;
        }

    if (tid < L) eRow[tid] = e_data[b * L + tid];

    // ---- h registers + bf16 LDS mirror init ----
    f32x4 hreg[4][4];   // [st][dt]: h[s][d0..3], s=(w*4+st)*16+lm, d0=dt*16+lk*4
    #pragma unroll
    for (int st = 0; st < 4; ++st) {
        const int s = (w * 4 + st) * 16 + lm;
        #pragma unroll
        for (int dt = 0; dt < 4; ++dt) {
            const int d0 = dt * 16 + lk * 4;
            f32x4 hv = {0.f, 0.f, 0.f, 0.f};
            if (s < S) hv = *(const f32x4*)(h0 + (size_t)s * 64 + d0);
            hreg[st][dt] = hv;
            const u32 lo = (u32)f2bf(hv.x) | ((u32)f2bf(hv.y) << 16);
            const u32 hi = (u32)f2bf(hv.z) | ((u32)f2bf(hv.w) << 16);
            *(uint2*)&hB[s * 72 + d0] = make_uint2(lo, hi);
        }
    }
    __syncthreads();
    qQ[0][tid] = (tid < S) ? q_matrix[(size_t)eRow[0] * S + tid] : 0.f;
    __syncthreads();

    // ---- h_tilde_0 = q[e_0] . h0 (register partials + shfl reduce) ----
    {
        f32x4 part[4];
        #pragma unroll
        for (int dt = 0; dt < 4; ++dt) part[dt] = f32x4{0.f, 0.f, 0.f, 0.f};
        #pragma unroll
        for (int st = 0; st < 4; ++st) {
            const int s = (w * 4 + st) * 16 + lm;
            const float qe = qQ[0][s];
            #pragma unroll
            for (int dt = 0; dt < 4; ++dt) part[dt] += qe * hreg[st][dt];
        }
        #pragma unroll
        for (int dt = 0; dt < 4; ++dt)
            #pragma unroll
            for (int i = 0; i < 4; ++i) {
                float v = part[dt][i];
                v += __shfl_xor(v, 1); v += __shfl_xor(v, 2);
                v += __shfl_xor(v, 4); v += __shfl_xor(v, 8);
                part[dt][i] = v;
            }
        if (lm == 0) {
            #pragma unroll
            for (int dt = 0; dt < 4; ++dt)
                *(f32x4*)&red[w * 64 + dt * 16 + lk * 4] = part[dt];
        }
        __syncthreads();
        if (tid < 64) {
            float sm = 0.f;
            #pragma unroll
            for (int ww = 0; ww < 8; ++ww) sm += red[ww * 64 + tid];
            htS[tid] = sm;
        }
        __syncthreads();
    }

    // ---------------- 99 steps, all intra-block ----------------
    for (int t = 0; t < L - 1; ++t) {
        const int cur = t & 1, nxt = cur ^ 1;

        // B-fragments: h rows (prev step's state) as bf16, b128 reads.
        // B layout (32x16): col n = lane&15 (s), k = (lane>>4)*8 + j
        short8v bfr[4][2];
        #pragma unroll
        for (int st = 0; st < 4; ++st) {
            const int s = (w * 4 + st) * 16 + lm;
            #pragma unroll
            for (int kc = 0; kc < 2; ++kc)
                bfr[st][kc] = *(const short8v*)&hB[s * 72 + kc * 32 + lk * 8];
        }

        // prefetch next q row + per-step gate constants
        const float qn = (tid < S) ? q_matrix[(size_t)eRow[t + 1] * S + tid] : 0.f;
        float g2v = 0.f, g3v = 0.f, g4v = 0.f;
        if (tid < 64) {
            g2v = G2[(b * L + t) * 64 + d];
            g3v = G3[(b * L + t) * 64 + d];
            g4v = G4it[(b * L + t) * 64 + d];
        }

        // gate partials: g2/g3 += W2h/W3h @ h_tilde_t (512-thread split over k)
        {
            float p2 = 0.f, p3 = 0.f;
            #pragma unroll
            for (int j = 0; j < 8; ++j) {
                const float hv = htS[kg * 8 + j];
                p2 += w2r[j] * hv;
                p3 += w3r[j] * hv;
            }
            red[kg * 64 + d] = p2;
            red2[kg * 64 + d] = p3;
        }
        qQ[nxt][tid] = qn;
        __syncthreads();                                    // (1) also fences bfr reads vs hB writes
        if (tid < 64) {
            float g2 = g2v, g3 = g3v;
            #pragma unroll
            for (int ww = 0; ww < 8; ++ww) { g2 += red[ww * 64 + d]; g3 += red2[ww * 64 + d]; }
            LGs[d] = sigm(g3) * (tanhf(g2) + 1.0f) * 0.5f;
        }
        __syncthreads();                                    // (2)
        {
            float pv = 0.f;
            #pragma unroll
            for (int j = 0; j < 8; ++j) pv += wbr[j] * LGs[kg * 8 + j];
            red[kg * 64 + d] = pv;
        }
        __syncthreads();                                    // (3)
        if (tid < 64) {
            float v = g4v;
            #pragma unroll
            for (int ww = 0; ww < 8; ++ww) v += red[ww * 64 + d];
            Vs[d] = v;
        }
        __syncthreads();                                    // (4)

        // MFMA + epilogue in two d-halves (caps live acc at 32 VGPR)
        f32x4 part[4];
        #pragma unroll
        for (int dt = 0; dt < 4; ++dt) part[dt] = f32x4{0.f, 0.f, 0.f, 0.f};

        #pragma unroll
        for (int half = 0; half < 2; ++half) {
            f32x4 acc[2][4];
            #pragma unroll
            for (int d2 = 0; d2 < 2; ++d2)
                #pragma unroll
                for (int st = 0; st < 4; ++st) acc[d2][st] = f32x4{0.f, 0.f, 0.f, 0.f};

            #pragma unroll
            for (int d2 = 0; d2 < 2; ++d2) {
                const int dt = half * 2 + d2;
                #pragma unroll
                for (int st = 0; st < 4; ++st) {
                    acc[d2][st] = __builtin_amdgcn_mfma_f32_16x16x32_bf16(
                        afr[dt][0], bfr[st][0], acc[d2][st], 0, 0, 0);
                    acc[d2][st] = __builtin_amdgcn_mfma_f32_16x16x32_bf16(
                        afr[dt][1], bfr[st][1], acc[d2][st], 0, 0, 0);
                }
            }

            #pragma unroll
            for (int d2 = 0; d2 < 2; ++d2) {
                const int dt = half * 2 + d2;
                const int d0 = dt * 16 + lk * 4;
                const f32x4 lg4 = *(const f32x4*)&LGs[d0];
                const f32x4 v4  = *(const f32x4*)&Vs[d0];
                #pragma unroll
                for (int st = 0; st < 4; ++st) {
                    const int s = (w * 4 + st) * 16 + lm;
                    const float qe = qQ[cur][s];
                    const float qq = qQ[nxt][s];
                    const f32x4 a  = acc[d2][st];
                    const f32x4 ho = hreg[st][dt];
                    f32x4 hn;
                    hn.x = qe * lg4.x + sigm(a.x + v4.x) * ho.x;
                    hn.y = qe * lg4.y + sigm(a.y + v4.y) * ho.y;
                    hn.z = qe * lg4.z + sigm(a.z + v4.z) * ho.z;
                    hn.w = qe * lg4.w + sigm(a.w + v4.w) * ho.w;
                    hreg[st][dt] = hn;
                    const u32 lo = (u32)f2bf(hn.x) | ((u32)f2bf(hn.y) << 16);
                    const u32 hi = (u32)f2bf(hn.z) | ((u32)f2bf(hn.w) << 16);
                    *(uint2*)&hB[s * 72 + d0] = make_uint2(lo, hi);
                    part[dt] += qq * hn;
                }
            }
        }

        // h_tilde_{t+1}: shfl over the 16 s-lanes, then 8-wave LDS reduce
        #pragma unroll
        for (int dt = 0; dt < 4; ++dt)
            #pragma unroll
            for (int i = 0; i < 4; ++i) {
                float v = part[dt][i];
                v += __shfl_xor(v, 1); v += __shfl_xor(v, 2);
                v += __shfl_xor(v, 4); v += __shfl_xor(v, 8);
                part[dt][i] = v;
            }
        if (lm == 0) {
            #pragma unroll
            for (int dt = 0; dt < 4; ++dt)
                *(f32x4*)&red[w * 64 + dt * 16 + lk * 4] = part[dt];
        }
        __syncthreads();                                    // (5)
        if (tid < 64) {
            float sm = 0.f;
            #pragma unroll
            for (int ww = 0; ww < 8; ++ww) sm += red[ww * 64 + tid];
            htS[tid] = sm;
            hthist[(size_t)(t + 1) * (B * 64) + b * 64 + tid] = sm;
        }
        __syncthreads();                                    // (6)
    }
}

// ---------------- epilogue: y_t for t=1..99 --------------------------------
__global__ __launch_bounds__(64) void k_y(
    const float* __restrict__ hthist, const float* __restrict__ prey,
    const float* __restrict__ W5T, float* __restrict__ pred)
{
    __shared__ float HT[64];
    const int j = blockIdx.x + 1;    // 1..99
    const int b = blockIdx.y;
    const int d = threadIdx.x;
    HT[d] = hthist[(size_t)j * (B * 64) + b * 64 + d];
    __syncthreads();
    float acc = prey[(b * L + j) * 64 + d];
    #pragma unroll 8
    for (int k = 0; k < 64; ++k) acc += W5T[(128 + k) * 64 + d] * HT[k];
    float y = sigm(acc);
    #pragma unroll
    for (int m = 1; m < 64; m <<= 1) y += __shfl_xor(y, m);
    if (d == 0) pred[b * L + j] = y * (1.0f / 64.0f);
}

} // namespace

extern "C" void kernel_launch(void* const* d_in, const int* in_sizes, int n_in,
                              void* d_out, int out_size, void* d_ws, size_t ws_size,
                              hipStream_t stream)
{
    const int*   e_data   = (const int*)d_in[0];
    const int*   a_data   = (const int*)d_in[1];
    const int*   at_data  = (const int*)d_in[2];
    const int*   it_data  = (const int*)d_in[3];
    const float* q_matrix = (const float*)d_in[4];
    const float* h0       = (const float*)d_in[5];
    const float* e_embed  = (const float*)d_in[6];
    const float* at_embed = (const float*)d_in[7];
    const float* it_embed = (const float*)d_in[8];
    const float* W1 = (const float*)d_in[9];  const float* b1 = (const float*)d_in[10];
    const float* W2 = (const float*)d_in[11]; const float* b2 = (const float*)d_in[12];
    const float* W3 = (const float*)d_in[13]; const float* b3 = (const float*)d_in[14];
    const float* W4 = (const float*)d_in[15]; const float* b4 = (const float*)d_in[16];
    const float* W5 = (const float*)d_in[17]; const float* b5 = (const float*)d_in[18];
    float* pred = (float*)d_out;

    float* ws   = (float*)d_ws;
    float* W1T    = ws;                        // 16384
    float* W2T    = W1T    + 16384;            // 16384
    float* W3T    = W2T    + 16384;            // 16384
    float* W4T    = W3T    + 16384;            // 12288
    float* W5T    = W4T    + 12288;            // 12288
    float* allL   = W5T    + 12288;            // 204800
    float* G2     = allL   + 204800;
    float* G3     = G2     + 204800;
    float* G4it   = G3     + 204800;
    float* prey   = G4it   + 204800;
    float* hthist = prey   + 204800;           // L*B*64 = 204800
    // total ~5.2 MB

    hipLaunchKernelGGL(k_init, dim3(64), dim3(256), 0, stream,
                       W1, W2, W3, W4, W5, W1T, W2T, W3T, W4T, W5T, pred);
    hipLaunchKernelGGL(k_all_learning, dim3(B * L / 4), dim3(256), 0, stream,
                       e_data, a_data, at_data, e_embed, at_embed, W1T, b1, allL);
    hipLaunchKernelGGL(k_pre, dim3(B * L / 4), dim3(256), 0, stream,
                       e_data, it_data, e_embed, it_embed, allL,
                       W2T, W3T, W4T, W5T, b2, b3, b4, b5, G2, G3, G4it, prey);
    hipLaunchKernelGGL(k_steps, dim3(B), dim3(512), 0, stream,
                       G2, G3, G4it, W2, W3, W4, q_matrix, e_data, h0, hthist);
    hipLaunchKernelGGL(k_y, dim3(L - 1, B), dim3(64), 0, stream,
                       hthist, prey, W5T, pred);
}